// Round 3
// baseline (1440.753 us; speedup 1.0000x reference)
//
#include <hip/hip_runtime.h>

#define NP 65536
#define EPSF 1e-12f

// ---- workspace layout (float offsets), per-batch reuse; peak 121.3 MB ----
#define OFF_PRE   0L            // qk_pre: 384*65536 = 25,165,824 floats
                                // (v-phase: v_pre at 0, vdw at +12,582,912)
#define OFF_VDW   12582912L
#define OFF_GRAMP 25165824L     // 512 blocks * 4 heads * 2304 = 4,718,592
#define OFF_NQP   29884416L     // 1024 * 192 = 196,608
#define OFF_NKP   30081024L     // 196,608
#define OFF_GRAM  30277632L     // 4*48*48 = 9,216
#define OFF_NRM   30286848L     // 384 (q norms^2 [0:192], k norms^2 [192:384])
#define OFF_M     30287232L     // 192*192 = 36,864
#define WS_NEED_FLOATS 30324096L
// = 121,296,384 bytes

// ---------------------------------------------------------------------------
// C = A(OCx192) @ X(192xNP), row-major. Tiles 64oc x 128px, 256 threads.
// grid = dim3(512, OC/64, 1). Used for qk 1x1 conv, v 1x1 conv, and M@v.
// ---------------------------------------------------------------------------
__global__ __launch_bounds__(256) void gemm_cn(
    const float* __restrict__ A,
    const float* __restrict__ X,
    float* __restrict__ Out)
{
    const int px0 = blockIdx.x * 128;
    const int oc0 = blockIdx.y * 64;
    const int tid = threadIdx.x;
    const int tx = tid & 31;   // px group of 4
    const int ty = tid >> 5;   // oc group of 8

    __shared__ float As[16][68];
    __shared__ float Xs[16][132];

    float acc[8][4];
    #pragma unroll
    for (int i = 0; i < 8; i++)
        #pragma unroll
        for (int j = 0; j < 4; j++) acc[i][j] = 0.f;

    for (int kb = 0; kb < 192; kb += 16) {
        { // stage A tile (64 oc x 16 k), transposed to As[k][oc]
            int oc = tid >> 2;
            int k0 = (tid & 3) * 4;
            const float4 av = *(const float4*)&A[(long)(oc0 + oc) * 192 + kb + k0];
            As[k0 + 0][oc] = av.x;
            As[k0 + 1][oc] = av.y;
            As[k0 + 2][oc] = av.z;
            As[k0 + 3][oc] = av.w;
        }
        { // stage X tile (16 k x 128 px)
            int r = tid >> 4;
            int f4 = tid & 15;
            const float* xrow = &X[(long)(kb + r) * NP + px0];
            *(float4*)&Xs[r][f4 * 4]      = *(const float4*)&xrow[f4 * 4];
            *(float4*)&Xs[r][64 + f4 * 4] = *(const float4*)&xrow[64 + f4 * 4];
        }
        __syncthreads();
        #pragma unroll
        for (int k = 0; k < 16; k++) {
            float4 a0 = *(const float4*)&As[k][ty * 8];
            float4 a1 = *(const float4*)&As[k][ty * 8 + 4];
            float4 xv = *(const float4*)&Xs[k][tx * 4];
            float av[8] = {a0.x, a0.y, a0.z, a0.w, a1.x, a1.y, a1.z, a1.w};
            float xl[4] = {xv.x, xv.y, xv.z, xv.w};
            #pragma unroll
            for (int i = 0; i < 8; i++)
                #pragma unroll
                for (int j = 0; j < 4; j++)
                    acc[i][j] = fmaf(av[i], xl[j], acc[i][j]);
        }
        __syncthreads();
    }
    #pragma unroll
    for (int i = 0; i < 8; i++) {
        float4 o4 = make_float4(acc[i][0], acc[i][1], acc[i][2], acc[i][3]);
        *(float4*)&Out[(long)(oc0 + ty * 8 + i) * NP + px0 + tx * 4] = o4;
    }
}

// ---------------------------------------------------------------------------
// Per batch: depthwise 3x3 on q,k pre-activations, per-channel norm partials
// (raw, unmasked), masked q/k staged in LDS, per-block 48x48 Gram partials
// per head. Tile 16x8 px, 128 threads, 512 blocks. No atomics.
// pre: [q(192ch); k(192ch)] x NP.  wdw rows: q -> ch, k -> 192+ch.
// ---------------------------------------------------------------------------
__global__ __launch_bounds__(128) void dwqk_fused(
    const float* __restrict__ pre, const float* __restrict__ wdw,
    const float* __restrict__ mask,
    float* __restrict__ gramP, float* __restrict__ nqp, float* __restrict__ nkp)
{
    const int blin = blockIdx.y * 16 + blockIdx.x;   // 0..511
    const int tx0 = blockIdx.x * 16, ty0 = blockIdx.y * 8;
    const int t = threadIdx.x;
    const int px = t & 15, py = t >> 4;
    const int X = tx0 + px, Y = ty0 + py;
    const int n = Y * 256 + X;
    const float m = mask[n];

    __shared__ float qs[48][132];
    __shared__ float ks[48][132];

    int offs[9]; bool val[9];
    {
        int ii = 0;
        for (int dy = -1; dy <= 1; dy++)
            for (int dx = -1; dx <= 1; dx++, ii++) {
                int yy = Y + dy, xx = X + dx;
                val[ii] = (yy >= 0 && yy < 256 && xx >= 0 && xx < 256);
                offs[ii] = dy * 256 + dx;
            }
    }

    const int i = t >> 3, j = t & 7;  // gram block: rows 3i.., cols 6j..

    for (int h = 0; h < 4; h++) {
        for (int c = 0; c < 48; c++) {
            int ch = h * 48 + c;
            { // q channel
                const float* p = pre + (long)ch * NP + n;
                const float* wp = wdw + ch * 9;
                float s = 0.f;
                #pragma unroll
                for (int k = 0; k < 9; k++)
                    s = fmaf(val[k] ? p[offs[k]] : 0.f, wp[k], s);
                float r = s * s;
                #pragma unroll
                for (int off = 32; off; off >>= 1) r += __shfl_down(r, off);
                if ((t & 63) == 0)
                    nqp[((long)blin * 2 + (t >> 6)) * 192 + ch] = r;
                qs[c][t] = s * m;
            }
            { // k channel
                const float* p = pre + (long)(192 + ch) * NP + n;
                const float* wp = wdw + (192 + ch) * 9;
                float s = 0.f;
                #pragma unroll
                for (int k = 0; k < 9; k++)
                    s = fmaf(val[k] ? p[offs[k]] : 0.f, wp[k], s);
                float r = s * s;
                #pragma unroll
                for (int off = 32; off; off >>= 1) r += __shfl_down(r, off);
                if ((t & 63) == 0)
                    nkp[((long)blin * 2 + (t >> 6)) * 192 + ch] = r;
                ks[c][t] = s * m;
            }
        }
        __syncthreads();
        // Gram over this tile: thread owns 3x6 pair block, dot over 128 px
        float acc[3][6];
        #pragma unroll
        for (int a = 0; a < 3; a++)
            #pragma unroll
            for (int d = 0; d < 6; d++) acc[a][d] = 0.f;
        for (int p = 0; p < 128; p += 4) {
            float4 qv[3], kv[6];
            #pragma unroll
            for (int a = 0; a < 3; a++) qv[a] = *(const float4*)&qs[3 * i + a][p];
            #pragma unroll
            for (int d = 0; d < 6; d++) kv[d] = *(const float4*)&ks[6 * j + d][p];
            #pragma unroll
            for (int a = 0; a < 3; a++)
                #pragma unroll
                for (int d = 0; d < 6; d++)
                    acc[a][d] += qv[a].x * kv[d].x + qv[a].y * kv[d].y +
                                 qv[a].z * kv[d].z + qv[a].w * kv[d].w;
        }
        float* gp = gramP + ((long)blin * 4 + h) * 2304;
        #pragma unroll
        for (int a = 0; a < 3; a++)
            #pragma unroll
            for (int d = 0; d < 6; d++)
                gp[(3 * i + a) * 48 + 6 * j + d] = acc[a][d];
        __syncthreads();
    }
}

// ---------------------------------------------------------------------------
// Depthwise 3x3 for v channels (192). One block = one (channel,row).
// ---------------------------------------------------------------------------
__global__ __launch_bounds__(256) void dwv_k(
    const float* __restrict__ vpre, const float* __restrict__ wdw,
    float* __restrict__ vdw)
{
    const int c = blockIdx.y;          // 0..191
    const int y = blockIdx.x;          // 0..255
    const int x = threadIdx.x;         // 0..255
    const float* p = vpre + (long)c * NP + y * 256 + x;
    const float* wp = wdw + (384 + c) * 9;
    float s = 0.f;
    int ii = 0;
    #pragma unroll
    for (int dy = -1; dy <= 1; dy++)
        #pragma unroll
        for (int dx = -1; dx <= 1; dx++, ii++) {
            int yy = y + dy, xx = x + dx;
            float v = (yy >= 0 && yy < 256 && xx >= 0 && xx < 256)
                          ? p[dy * 256 + dx] : 0.f;
            s = fmaf(v, wp[ii], s);
        }
    vdw[(long)c * NP + y * 256 + x] = s;
}

// ---------------------------------------------------------------------------
// Reduce partials (per batch): 9216 gram sums (over 512) + 384 norm sums
// (over 1024 wave-rows). 38 blocks x 256 threads, guarded.
// ---------------------------------------------------------------------------
__global__ __launch_bounds__(256) void reduce_k(
    const float* __restrict__ gramP, const float* __restrict__ nqp,
    const float* __restrict__ nkp, float* __restrict__ gram,
    float* __restrict__ nrm)
{
    int idx = blockIdx.x * 256 + threadIdx.x;
    if (idx < 9216) {
        const float* p = gramP + idx;
        float s = 0.f;
        #pragma unroll 8
        for (int blk = 0; blk < 512; blk++) s += p[(long)blk * 9216];
        gram[idx] = s;
    } else if (idx < 9600) {
        int i2 = idx - 9216;                    // 0..383
        int qk = i2 / 192, ch = i2 % 192;
        const float* p = (qk ? nkp : nqp) + ch;
        float s = 0.f;
        #pragma unroll 8
        for (int r = 0; r < 1024; r++) s += p[(long)r * 192];
        nrm[i2] = s;
    }
}

// ---------------------------------------------------------------------------
// Per head (4 blocks): scale gram by norms+temperature, softmax rows,
// fold Wproj:  M[o][h*48+d] = sum_c Wproj[o][h*48+c] * attn[c][d]
// ---------------------------------------------------------------------------
__global__ __launch_bounds__(256) void finalize_k(
    const float* __restrict__ gram, const float* __restrict__ nrm,
    const float* __restrict__ wproj, const float* __restrict__ temp,
    float* __restrict__ M)
{
    int h = blockIdx.x;
    int t = threadIdx.x;
    __shared__ float attn[48][49];
    __shared__ float qn[48], kn[48];
    if (t < 96) {
        int c = t % 48;
        int ch = h * 48 + c;
        float v = nrm[(t < 48 ? 0 : 192) + ch];
        float s = fmaxf(sqrtf(v), EPSF);
        if (t < 48) qn[c] = s; else kn[c] = s;
    }
    __syncthreads();
    float tp = temp[h];
    for (int idx = t; idx < 2304; idx += 256) {
        int c = idx / 48, d = idx % 48;
        attn[c][d] = gram[(h * 48 + c) * 48 + d] * tp / (qn[c] * kn[d]);
    }
    __syncthreads();
    if (t < 48) {
        float mx = -1e30f;
        for (int d = 0; d < 48; d++) mx = fmaxf(mx, attn[t][d]);
        float s = 0.f;
        for (int d = 0; d < 48; d++) {
            float e = expf(attn[t][d] - mx);
            attn[t][d] = e; s += e;
        }
        float inv = 1.f / s;
        for (int d = 0; d < 48; d++) attn[t][d] *= inv;
    }
    __syncthreads();
    for (int idx = t; idx < 9216; idx += 256) {
        int o = idx / 48, d = idx % 48;
        float s = 0.f;
        #pragma unroll
        for (int c = 0; c < 48; c++)
            s = fmaf(wproj[o * 192 + h * 48 + c], attn[c][d], s);
        M[o * 192 + h * 48 + d] = s;
    }
}

// ---------------------------------------------------------------------------
extern "C" void kernel_launch(void* const* d_in, const int* in_sizes, int n_in,
                              void* d_out, int out_size, void* d_ws, size_t ws_size,
                              hipStream_t stream) {
    const float* x     = (const float*)d_in[0];
    const float* mask  = (const float*)d_in[1];
    const float* wqkv  = (const float*)d_in[2];
    const float* wdw   = (const float*)d_in[3];
    const float* wproj = (const float*)d_in[4];
    const float* temp  = (const float*)d_in[5];
    float* out = (float*)d_out;
    float* ws  = (float*)d_ws;

    // refuse cleanly (wrong output, no fault) if workspace is too small
    if (ws_size < (size_t)WS_NEED_FLOATS * sizeof(float)) return;

    float* pre   = ws + OFF_PRE;   // qk_pre, later v_pre
    float* vdw   = ws + OFF_VDW;
    float* gramP = ws + OFF_GRAMP;
    float* nqp   = ws + OFF_NQP;
    float* nkp   = ws + OFF_NKP;
    float* gram  = ws + OFF_GRAM;
    float* nrm   = ws + OFF_NRM;
    float* Mbuf  = ws + OFF_M;

    for (int b = 0; b < 2; b++) {
        const float* xb    = x    + (long)b * 192 * NP;
        const float* maskb = mask + (long)b * NP;
        float*       outb  = out  + (long)b * 192 * NP;

        // qk_pre = Wqk @ x[b]   (384x192 @ 192x65536)
        gemm_cn<<<dim3(512, 6, 1), 256, 0, stream>>>(wqkv, xb, pre);
        // dw conv + gram/norm partials
        dwqk_fused<<<dim3(16, 32, 1), 128, 0, stream>>>(
            pre, wdw, maskb, gramP, nqp, nkp);
        // reduce partials
        reduce_k<<<38, 256, 0, stream>>>(gramP, nqp, nkp, gram, nrm);
        // softmax + Wproj fold -> M
        finalize_k<<<4, 256, 0, stream>>>(gram, nrm, wproj, temp, Mbuf);
        // v_pre = Wv @ x[b]   (192x192 @ 192x65536), reuses pre region
        gemm_cn<<<dim3(512, 3, 1), 256, 0, stream>>>(wqkv + 384 * 192, xb, pre);
        // depthwise on v
        dwv_k<<<dim3(256, 192, 1), 256, 0, stream>>>(pre, wdw, vdw);
        // out[b] = M @ vdw   (192x192 @ 192x65536)
        gemm_cn<<<dim3(512, 3, 1), 256, 0, stream>>>(Mbuf, vdw, outb);
    }
}

// Round 4
// 1405.012 us; speedup vs baseline: 1.0254x; 1.0254x over previous
//
#include <hip/hip_runtime.h>

#define NP 65536
#define EPSF 1e-12f

// ---- workspace layout (float offsets), per-batch reuse; peak 110.7 MB ----
#define OFF_PRE   0L            // qk_pre: 384*65536 = 25,165,824 floats
                                // (v-phase: v_pre at 0, vdw at +12,582,912)
#define OFF_VDW   12582912L
#define OFF_GRAMP 25165824L     // 256 rows * 4 heads * 2304 = 2,359,296
#define OFF_NQKP  27525120L     // 384 ch * 256 rows = 98,304
#define OFF_GRAM  27623424L     // 4*48*48 = 9,216
#define OFF_NRM   27632640L     // 384 (q norms^2 [0:192], k norms^2 [192:384])
#define OFF_M     27633024L     // 192*192 = 36,864
#define WS_NEED_FLOATS 27669888L
// = 110,679,552 bytes (known-safe: round-3 guard of 121.3 MB passed)

// ---------------------------------------------------------------------------
// C = A(OCx192) @ X(192xNP), row-major. Tiles 64oc x 128px, 256 threads.
// grid = dim3(512, OC/64, 1). Used for qk 1x1 conv, v 1x1 conv, and M@v.
// ---------------------------------------------------------------------------
__global__ __launch_bounds__(256) void gemm_cn(
    const float* __restrict__ A,
    const float* __restrict__ X,
    float* __restrict__ Out)
{
    const int px0 = blockIdx.x * 128;
    const int oc0 = blockIdx.y * 64;
    const int tid = threadIdx.x;
    const int tx = tid & 31;   // px group of 4
    const int ty = tid >> 5;   // oc group of 8

    __shared__ float As[16][68];
    __shared__ float Xs[16][132];

    float acc[8][4];
    #pragma unroll
    for (int i = 0; i < 8; i++)
        #pragma unroll
        for (int j = 0; j < 4; j++) acc[i][j] = 0.f;

    for (int kb = 0; kb < 192; kb += 16) {
        { // stage A tile (64 oc x 16 k), transposed to As[k][oc]
            int oc = tid >> 2;
            int k0 = (tid & 3) * 4;
            const float4 av = *(const float4*)&A[(long)(oc0 + oc) * 192 + kb + k0];
            As[k0 + 0][oc] = av.x;
            As[k0 + 1][oc] = av.y;
            As[k0 + 2][oc] = av.z;
            As[k0 + 3][oc] = av.w;
        }
        { // stage X tile (16 k x 128 px)
            int r = tid >> 4;
            int f4 = tid & 15;
            const float* xrow = &X[(long)(kb + r) * NP + px0];
            *(float4*)&Xs[r][f4 * 4]      = *(const float4*)&xrow[f4 * 4];
            *(float4*)&Xs[r][64 + f4 * 4] = *(const float4*)&xrow[64 + f4 * 4];
        }
        __syncthreads();
        #pragma unroll
        for (int k = 0; k < 16; k++) {
            float4 a0 = *(const float4*)&As[k][ty * 8];
            float4 a1 = *(const float4*)&As[k][ty * 8 + 4];
            float4 xv = *(const float4*)&Xs[k][tx * 4];
            float av[8] = {a0.x, a0.y, a0.z, a0.w, a1.x, a1.y, a1.z, a1.w};
            float xl[4] = {xv.x, xv.y, xv.z, xv.w};
            #pragma unroll
            for (int i = 0; i < 8; i++)
                #pragma unroll
                for (int j = 0; j < 4; j++)
                    acc[i][j] = fmaf(av[i], xl[j], acc[i][j]);
        }
        __syncthreads();
    }
    #pragma unroll
    for (int i = 0; i < 8; i++) {
        float4 o4 = make_float4(acc[i][0], acc[i][1], acc[i][2], acc[i][3]);
        *(float4*)&Out[(long)(oc0 + ty * 8 + i) * NP + px0 + tx * 4] = o4;
    }
}

// ---------------------------------------------------------------------------
// Fused depthwise-3x3 + Gram + norms, restructured for occupancy.
// Block = (image row y, head h): grid (256, 4) = 1024 blocks, 256 threads.
// Staging computes dw inline from `pre` (halo rows hit L3), raw q/k in LDS.
// Gram: per-wave 48x48 via 6x6 register tiles over the wave's 32-px window,
// mask^2 folded at compute time from an LDS m2 tile. Norm partials read raw
// LDS rows. 4 wave partials merged in LDS; one partial per (row, head).
// ---------------------------------------------------------------------------
__global__ __launch_bounds__(256) void dwgram_k(
    const float* __restrict__ pre, const float* __restrict__ wdw,
    const float* __restrict__ mask,
    float* __restrict__ gramP, float* __restrict__ nqkp)
{
    const int y = blockIdx.x;          // image row 0..255
    const int h = blockIdx.y;          // head 0..3
    const int t = threadIdx.x;
    const int g = t >> 6;              // wave 0..3 (px window 32g..32g+31)
    const int u = t & 63;
    const int ti = u >> 3, tj = u & 7; // 8x8 -> 6x6 output block

    __shared__ float qs[48][132];
    __shared__ float ks[48][132];
    __shared__ float4 m2s4[32];

    float acc[6][6];
    #pragma unroll
    for (int a = 0; a < 6; a++)
        #pragma unroll
        for (int d = 0; d < 6; d++) acc[a][d] = 0.f;

    float nsum = 0.f;                  // norm partial (threads 0..95)
    const int col4 = t & 31;           // float4 column within 128-px subtile
    const int rgrp = t >> 5;           // 0..7 -> rows rgrp+8*iL

    for (int s = 0; s < 2; s++) {
        const int x0 = s * 128 + col4 * 4;   // global x of first staged output
        if (t < 32) {
            float4 mv = *(const float4*)&mask[y * 256 + s * 128 + t * 4];
            m2s4[t] = make_float4(mv.x * mv.x, mv.y * mv.y,
                                  mv.z * mv.z, mv.w * mv.w);
        }
        #pragma unroll
        for (int iL = 0; iL < 6; iL++) {
            const int r = rgrp + 8 * iL;     // 0..47
            #pragma unroll
            for (int side = 0; side < 2; side++) {
                const int ch = side ? (192 + h * 48 + r) : (h * 48 + r);
                const float* src = pre + (long)ch * NP + y * 256;
                const float* wp = wdw + ch * 9;
                float in3[3][6];
                #pragma unroll
                for (int dy = 0; dy < 3; dy++) {
                    const int yy = y + dy - 1;
                    const bool rv = (yy >= 0) && (yy < 256);
                    const float* rp = src + (dy - 1) * 256;
                    #pragma unroll
                    for (int uu = 0; uu < 6; uu++) {
                        const int xx = x0 + uu - 1;
                        in3[dy][uu] = (rv && xx >= 0 && xx < 256) ? rp[xx] : 0.f;
                    }
                }
                float o[4];
                #pragma unroll
                for (int q = 0; q < 4; q++) {
                    float sa = 0.f;
                    #pragma unroll
                    for (int dy = 0; dy < 3; dy++)
                        #pragma unroll
                        for (int dx = 0; dx < 3; dx++)
                            sa = fmaf(in3[dy][q + dx], wp[dy * 3 + dx], sa);
                    o[q] = sa;
                }
                float* dst = side ? &ks[r][col4 * 4] : &qs[r][col4 * 4];
                *(float4*)dst = make_float4(o[0], o[1], o[2], o[3]);
            }
        }
        __syncthreads();
        // Gram over this wave's 32-px window
        #pragma unroll
        for (int p = 0; p < 32; p += 4) {
            const int pp = 32 * g + p;
            const float4 m2 = m2s4[pp >> 2];
            float4 qm[6];
            #pragma unroll
            for (int a = 0; a < 6; a++) {
                float4 qv = *(const float4*)&qs[6 * ti + a][pp];
                qm[a] = make_float4(qv.x * m2.x, qv.y * m2.y,
                                    qv.z * m2.z, qv.w * m2.w);
            }
            #pragma unroll
            for (int d = 0; d < 6; d++) {
                const float4 kv = *(const float4*)&ks[6 * tj + d][pp];
                #pragma unroll
                for (int a = 0; a < 6; a++) {
                    acc[a][d] = fmaf(qm[a].x, kv.x, acc[a][d]);
                    acc[a][d] = fmaf(qm[a].y, kv.y, acc[a][d]);
                    acc[a][d] = fmaf(qm[a].z, kv.z, acc[a][d]);
                    acc[a][d] = fmaf(qm[a].w, kv.w, acc[a][d]);
                }
            }
        }
        // norm partials from raw LDS rows (unmasked, per reference)
        if (t < 96) {
            const float* row = (t < 48) ? &qs[t][0] : &ks[t - 48][0];
            #pragma unroll 8
            for (int p = 0; p < 128; p += 4) {
                float4 v = *(const float4*)&row[p];
                nsum = fmaf(v.x, v.x, nsum);
                nsum = fmaf(v.y, v.y, nsum);
                nsum = fmaf(v.z, v.z, nsum);
                nsum = fmaf(v.w, v.w, nsum);
            }
        }
        __syncthreads();
    }
    if (t < 96) {
        const int gch = (t < 48) ? (h * 48 + t) : (192 + h * 48 + (t - 48));
        nqkp[gch * 256 + y] = nsum;
    }
    // merge the 4 wave partials via LDS scratch (reuse qs)
    float* scratch = &qs[0][0];
    for (int gg = 0; gg < 4; gg++) {
        if (g == gg) {
            #pragma unroll
            for (int a = 0; a < 6; a++)
                #pragma unroll
                for (int d = 0; d < 6; d++) {
                    const int idx = (6 * ti + a) * 48 + 6 * tj + d;
                    if (gg == 0) scratch[idx] = acc[a][d];
                    else scratch[idx] += acc[a][d];
                }
        }
        __syncthreads();
    }
    float* gp = gramP + ((long)y * 4 + h) * 2304;
    for (int idx = t; idx < 2304; idx += 256) gp[idx] = scratch[idx];
}

// ---------------------------------------------------------------------------
// Depthwise 3x3 for v channels (192). One block = one (channel,row).
// ---------------------------------------------------------------------------
__global__ __launch_bounds__(256) void dwv_k(
    const float* __restrict__ vpre, const float* __restrict__ wdw,
    float* __restrict__ vdw)
{
    const int c = blockIdx.y;          // 0..191
    const int y = blockIdx.x;          // 0..255
    const int x = threadIdx.x;         // 0..255
    const float* p = vpre + (long)c * NP + y * 256 + x;
    const float* wp = wdw + (384 + c) * 9;
    float s = 0.f;
    int ii = 0;
    #pragma unroll
    for (int dy = -1; dy <= 1; dy++)
        #pragma unroll
        for (int dx = -1; dx <= 1; dx++, ii++) {
            int yy = y + dy, xx = x + dx;
            float v = (yy >= 0 && yy < 256 && xx >= 0 && xx < 256)
                          ? p[dy * 256 + dx] : 0.f;
            s = fmaf(v, wp[ii], s);
        }
    vdw[(long)c * NP + y * 256 + x] = s;
}

// ---------------------------------------------------------------------------
// Reduce partials (per batch): 9216 gram sums (over 256 row-blocks) + 384
// norm sums (over 256 rows, contiguous). 38 blocks x 256 threads, guarded.
// ---------------------------------------------------------------------------
__global__ __launch_bounds__(256) void reduce_k(
    const float* __restrict__ gramP, const float* __restrict__ nqkp,
    float* __restrict__ gram, float* __restrict__ nrm)
{
    int idx = blockIdx.x * 256 + threadIdx.x;
    if (idx < 9216) {
        const float* p = gramP + idx;
        float s = 0.f;
        #pragma unroll 8
        for (int blk = 0; blk < 256; blk++) s += p[(long)blk * 9216];
        gram[idx] = s;
    } else if (idx < 9600) {
        int i2 = idx - 9216;                    // channel 0..383
        const float* p = nqkp + (long)i2 * 256;
        float s = 0.f;
        #pragma unroll 8
        for (int r = 0; r < 256; r++) s += p[r];
        nrm[i2] = s;
    }
}

// ---------------------------------------------------------------------------
// Per head (4 blocks): scale gram by norms+temperature, softmax rows,
// fold Wproj:  M[o][h*48+d] = sum_c Wproj[o][h*48+c] * attn[c][d]
// ---------------------------------------------------------------------------
__global__ __launch_bounds__(256) void finalize_k(
    const float* __restrict__ gram, const float* __restrict__ nrm,
    const float* __restrict__ wproj, const float* __restrict__ temp,
    float* __restrict__ M)
{
    int h = blockIdx.x;
    int t = threadIdx.x;
    __shared__ float attn[48][49];
    __shared__ float qn[48], kn[48];
    if (t < 96) {
        int c = t % 48;
        int ch = h * 48 + c;
        float v = nrm[(t < 48 ? 0 : 192) + ch];
        float s = fmaxf(sqrtf(v), EPSF);
        if (t < 48) qn[c] = s; else kn[c] = s;
    }
    __syncthreads();
    float tp = temp[h];
    for (int idx = t; idx < 2304; idx += 256) {
        int c = idx / 48, d = idx % 48;
        attn[c][d] = gram[(h * 48 + c) * 48 + d] * tp / (qn[c] * kn[d]);
    }
    __syncthreads();
    if (t < 48) {
        float mx = -1e30f;
        for (int d = 0; d < 48; d++) mx = fmaxf(mx, attn[t][d]);
        float s = 0.f;
        for (int d = 0; d < 48; d++) {
            float e = expf(attn[t][d] - mx);
            attn[t][d] = e; s += e;
        }
        float inv = 1.f / s;
        for (int d = 0; d < 48; d++) attn[t][d] *= inv;
    }
    __syncthreads();
    for (int idx = t; idx < 9216; idx += 256) {
        int o = idx / 48, d = idx % 48;
        float s = 0.f;
        #pragma unroll
        for (int c = 0; c < 48; c++)
            s = fmaf(wproj[o * 192 + h * 48 + c], attn[c][d], s);
        M[o * 192 + h * 48 + d] = s;
    }
}

// ---------------------------------------------------------------------------
extern "C" void kernel_launch(void* const* d_in, const int* in_sizes, int n_in,
                              void* d_out, int out_size, void* d_ws, size_t ws_size,
                              hipStream_t stream) {
    const float* x     = (const float*)d_in[0];
    const float* mask  = (const float*)d_in[1];
    const float* wqkv  = (const float*)d_in[2];
    const float* wdw   = (const float*)d_in[3];
    const float* wproj = (const float*)d_in[4];
    const float* temp  = (const float*)d_in[5];
    float* out = (float*)d_out;
    float* ws  = (float*)d_ws;

    // refuse cleanly (wrong output, no fault) if workspace is too small
    if (ws_size < (size_t)WS_NEED_FLOATS * sizeof(float)) return;

    float* pre   = ws + OFF_PRE;   // qk_pre, later v_pre
    float* vdw   = ws + OFF_VDW;
    float* gramP = ws + OFF_GRAMP;
    float* nqkp  = ws + OFF_NQKP;
    float* gram  = ws + OFF_GRAM;
    float* nrm   = ws + OFF_NRM;
    float* Mbuf  = ws + OFF_M;

    for (int b = 0; b < 2; b++) {
        const float* xb    = x    + (long)b * 192 * NP;
        const float* maskb = mask + (long)b * NP;
        float*       outb  = out  + (long)b * 192 * NP;

        // qk_pre = Wqk @ x[b]   (384x192 @ 192x65536)
        gemm_cn<<<dim3(512, 6, 1), 256, 0, stream>>>(wqkv, xb, pre);
        // fused dw conv + gram + norm partials
        dwgram_k<<<dim3(256, 4, 1), 256, 0, stream>>>(
            pre, wdw, maskb, gramP, nqkp);
        // reduce partials
        reduce_k<<<38, 256, 0, stream>>>(gramP, nqkp, gram, nrm);
        // softmax + Wproj fold -> M
        finalize_k<<<4, 256, 0, stream>>>(gram, nrm, wproj, temp, Mbuf);
        // v_pre = Wv @ x[b]   (192x192 @ 192x65536), reuses pre region
        gemm_cn<<<dim3(512, 3, 1), 256, 0, stream>>>(wqkv + 384 * 192, xb, pre);
        // depthwise on v
        dwv_k<<<dim3(256, 192, 1), 256, 0, stream>>>(pre, wdw, vdw);
        // out[b] = M @ vdw   (192x192 @ 192x65536)
        gemm_cn<<<dim3(512, 3, 1), 256, 0, stream>>>(Mbuf, vdw, outb);
    }
}